// Round 10
// baseline (148.326 us; speedup 1.0000x reference)
//
#include <hip/hip_runtime.h>

#define HDIM 1024
#define NW 18                  // 6 gate rows + 12 expert rows (e*2+l)
#define NTHREADS 256
#define RPT 8                  // rows per wave per batch
#define ROWS_PER_BATCH (4 * RPT)   // 32 rows per block-batch
#define GRID 256               // persistent: 1 block/CU

typedef float f32x4 __attribute__((ext_vector_type(4)));

// R10: whole-wave row chunks (CL=64) — fill-kernel-equivalent DRAM footprint.
//  - Each x-load instruction: 64 lanes x 16B = 1KB CONTIGUOUS from one row
//    (one DRAM page per request; R7 issued 8 scattered 128B segments/instr).
//  - Wave owns 8 consecutive rows/batch; chunk index shared across the 8 rows
//    so the 18 weight ds_reads amortize over 8 rows.
//  - Weights in natural LDS layout [w][256] f32x4: lane-stride-1 ds_read_b128,
//    conflict-free, no swizzle.
//  - Persistent blocks (grid=256): weights staged ONCE; 8 batches per block with
//    cross-batch prefetch (no pipeline drain between batches).
//  - Chunk-phase rotation (R7's proven lever) over the 4 chunks.
//  - Final: 6-level butterfly reduce; lane k keeps row k's result; single
//    coalesced 64B float2 store by lanes 0..7.
__global__ __launch_bounds__(NTHREADS, 1)
void hardmoe_kernel(const float* __restrict__ cls,
                    const float* __restrict__ gate_w,
                    const float* __restrict__ gate_b,
                    const float* __restrict__ expert_w,
                    const float* __restrict__ expert_b,
                    float* __restrict__ out, int B)
{
    __shared__ f32x4 Wl[NW * 256];   // 72 KB, natural [w][slot] layout

    const int t  = threadIdx.x;
    const int wv = t >> 6;        // wave 0..3
    const int l  = t & 63;        // lane

    const int Bm1 = B - 1;
    const int nbatch = (B + ROWS_PER_BATCH - 1) / ROWS_PER_BATCH;

#define PREF(BUF, WBROW, JC)                                                     \
    _Pragma("unroll")                                                            \
    for (int k = 0; k < RPT; ++k) {                                              \
        int rr = (WBROW) + k; rr = rr < Bm1 ? rr : Bm1;                          \
        BUF[k] = __builtin_nontemporal_load(reinterpret_cast<const f32x4*>(     \
            cls + (size_t)rr * HDIM + (JC) * 256 + (l << 2)));                   \
    }

#define COMP(BUF, JC)                                                            \
    _Pragma("unroll")                                                            \
    for (int w = 0; w < NW; ++w) {                                               \
        f32x4 wf = Wl[w * 256 + (JC) * 64 + l];                                  \
        _Pragma("unroll")                                                        \
        for (int k = 0; k < RPT; ++k) {                                          \
            float a = acc[k][w];                                                 \
            a = fmaf(BUF[k].x, wf.x, a);                                         \
            a = fmaf(BUF[k].y, wf.y, a);                                         \
            a = fmaf(BUF[k].z, wf.z, a);                                         \
            a = fmaf(BUF[k].w, wf.w, a);                                         \
            acc[k][w] = a;                                                       \
        }                                                                        \
    }

    // ---- First-batch prefetch issued BEFORE the staging barrier (overlaps) ----
    int bt = blockIdx.x;
    int wb = bt * ROWS_PER_BATCH + wv * RPT;
    int phase = (blockIdx.x + wv) & 3;
    f32x4 xA[RPT], xB[RPT];
    PREF(xA, wb, phase);

    // ---- Stage weights: thread t owns f4-slot t for each w (coalesced) ----
#pragma unroll
    for (int w = 0; w < NW; ++w) {
        const float* src = (w < 6) ? (gate_w + (size_t)w * HDIM)
                                   : (expert_w + (size_t)(w - 6) * HDIM);
        Wl[w * 256 + t] = *(reinterpret_cast<const f32x4*>(src) + t);
    }

    // ---- Biases (uniform -> scalar) ----
    float gb[6], eb[12];
#pragma unroll
    for (int e = 0; e < 6; ++e) gb[e] = gate_b[e];
#pragma unroll
    for (int k = 0; k < 12; ++k) eb[k] = expert_b[k];

    __syncthreads();

    for (int it = 0; bt < nbatch; ++it) {
        float acc[RPT][NW];
#pragma unroll
        for (int k = 0; k < RPT; ++k)
#pragma unroll
            for (int w = 0; w < NW; ++w) acc[k][w] = 0.f;

        const int jc0 = phase;
        const int jc1 = (phase + 1) & 3;
        const int jc2 = (phase + 2) & 3;
        const int jc3 = (phase + 3) & 3;

        // step 0: prefetch chunk1 -> xB, compute chunk0 from xA
        PREF(xB, wb, jc1);
        COMP(xA, jc0);
        // step 1: prefetch chunk2 -> xA, compute chunk1 from xB
        PREF(xA, wb, jc2);
        COMP(xB, jc1);
        // step 2: prefetch chunk3 -> xB, compute chunk2 from xA
        PREF(xB, wb, jc3);
        COMP(xA, jc2);
        // step 3: prefetch NEXT batch chunk0 -> xA, compute chunk3 from xB
        const int btn = bt + GRID;
        const int wbn = btn * ROWS_PER_BATCH + wv * RPT;
        const int phasen = (blockIdx.x + wv + it + 1) & 3;
        if (btn < nbatch) { PREF(xA, wbn, phasen); }
        COMP(xB, jc3);

        // ---- Butterfly reduce across all 64 lanes ----
#pragma unroll
        for (int k = 0; k < RPT; ++k)
#pragma unroll
            for (int w = 0; w < NW; ++w) {
                float v = acc[k][w];
                v += __shfl_xor(v, 1);
                v += __shfl_xor(v, 2);
                v += __shfl_xor(v, 4);
                v += __shfl_xor(v, 8);
                v += __shfl_xor(v, 16);
                v += __shfl_xor(v, 32);
                acc[k][w] = v;
            }

        // ---- Per row: argmax (strict >, first-max) + expert select; lane k keeps row k ----
        float so0 = 0.f, so1 = 0.f;
#pragma unroll
        for (int k = 0; k < RPT; ++k) {
            float best = acc[k][0] + gb[0];
            int idx = 0;
#pragma unroll
            for (int e = 1; e < 6; ++e) {
                float v = acc[k][e] + gb[e];
                if (v > best) { best = v; idx = e; }
            }
            float o0 = 0.f, o1 = 0.f;
#pragma unroll
            for (int e = 0; e < 6; ++e) {
                bool m = (idx == e);
                o0 = m ? (acc[k][6 + 2 * e] + eb[2 * e])     : o0;
                o1 = m ? (acc[k][7 + 2 * e] + eb[2 * e + 1]) : o1;
            }
            so0 = (l == k) ? o0 : so0;
            so1 = (l == k) ? o1 : so1;
        }
        if (l < RPT) {
            const int row = wb + l;
            if (row < B)
                *reinterpret_cast<float2*>(out + (size_t)row * 2) = make_float2(so0, so1);
        }

        bt = btn; wb = wbn; phase = phasen;
    }

#undef PREF
#undef COMP
}

extern "C" void kernel_launch(void* const* d_in, const int* in_sizes, int n_in,
                              void* d_out, int out_size, void* d_ws, size_t ws_size,
                              hipStream_t stream) {
    const float* cls      = (const float*)d_in[0];
    const float* gate_w   = (const float*)d_in[1];
    const float* gate_b   = (const float*)d_in[2];
    const float* expert_w = (const float*)d_in[3];
    const float* expert_b = (const float*)d_in[4];
    float* out = (float*)d_out;

    const int B = in_sizes[0] / HDIM;

    hardmoe_kernel<<<GRID, NTHREADS, 0, stream>>>(cls, gate_w, gate_b,
                                                  expert_w, expert_b, out, B);
}

// Round 11
// 51.331 us; speedup vs baseline: 2.8896x; 2.8896x over previous
//
#include <hip/hip_runtime.h>

#define HDIM 1024
#define NW 18                 // 6 gate rows + 12 expert rows (e*2+l)
#define NTHREADS 256
#define RPT 8                 // rows per lane
#define ROWS_PER_BLOCK 256    // 4 waves x 64 rows
#define NJ 32                 // j-steps of 32 floats (128B) per row

typedef float f32x4 __attribute__((ext_vector_type(4)));

// R11 = R7 (best, 56.2us) with ONE change: plain loads instead of nontemporal.
//  - R10 revealed cls (256MiB) becomes L3-resident across graph replays
//    (steady-state FETCH ~0.5MB). If the nt bit was inhibiting LLC
//    allocation/hits, plain loads turn the timed replays into L3-fed runs
//    (ceiling >> HBM 6.3TB/s). Single-variable test.
//  - Everything else identical to R7: 8-lane clusters (128B chunks), RPT=8,
//    LDS-broadcast weights [slot][w] f32x4 (72KB), inter-wave phase rotation,
//    distance-1 static double buffer, launch_bounds(256,1), grid 256.
__global__ __launch_bounds__(NTHREADS, 1)
void hardmoe_kernel(const float* __restrict__ cls,
                    const float* __restrict__ gate_w,
                    const float* __restrict__ gate_b,
                    const float* __restrict__ expert_w,
                    const float* __restrict__ expert_b,
                    float* __restrict__ out, int B)
{
    __shared__ f32x4 Wl[256 * NW];   // 72 KB

    const int t = threadIdx.x;

    // ---- Stage weights: thread t owns f4-slot s=t for all 18 w ----
    {
        const int s = t;
#pragma unroll
        for (int w = 0; w < NW; ++w) {
            const float* src = (w < 6) ? (gate_w + (size_t)w * HDIM)
                                       : (expert_w + (size_t)(w - 6) * HDIM);
            Wl[s * NW + w] = *(reinterpret_cast<const f32x4*>(src) + s);
        }
    }

    // ---- Biases (uniform -> scalar) ----
    float gb[6], eb[12];
#pragma unroll
    for (int e = 0; e < 6; ++e) gb[e] = gate_b[e];
#pragma unroll
    for (int k = 0; k < 12; ++k) eb[k] = expert_b[k];

    __syncthreads();

    const int wv = t >> 6;       // wave 0..3
    const int l  = t & 63;
    const int s8 = l >> 3;       // cluster 0..7
    const int c  = l & 7;        // col sublane 0..7

    // Even phase in [0,32), spread over blocks and waves (R7's proven lever).
    const int phase = ((blockIdx.x << 3) + (wv << 1)) & (NJ - 1);

    const int wavebase = blockIdx.x * ROWS_PER_BLOCK + wv * 64;

    const float* px[RPT];
    int rows[RPT];
#pragma unroll
    for (int k = 0; k < RPT; ++k) {
        int r = wavebase + k * 8 + s8;
        rows[k] = r;
        int rc = r < B ? r : B - 1;
        px[k] = cls + (size_t)rc * HDIM + c * 4;
    }

    float acc[RPT][NW];
#pragma unroll
    for (int k = 0; k < RPT; ++k)
#pragma unroll
        for (int w = 0; w < NW; ++w) acc[k][w] = 0.f;

    f32x4 xA[RPT], xB[RPT];
#pragma unroll
    for (int k = 0; k < RPT; ++k)
        xA[k] = *reinterpret_cast<const f32x4*>(px[k] + (size_t)phase * 32);

    for (int jj = 0; jj < NJ; jj += 2) {
        const int ja = (jj + phase) & (NJ - 1);
        const int jb = (jj + 1 + phase) & (NJ - 1);
        const int jc = (jj + 2 + phase) & (NJ - 1);

        // prefetch column jb
#pragma unroll
        for (int k = 0; k < RPT; ++k)
            xB[k] = *reinterpret_cast<const f32x4*>(px[k] + (size_t)jb * 32);
        // compute column ja with xA
        {
            const f32x4* wp = &Wl[(ja * 8 + c) * NW];
#pragma unroll
            for (int w = 0; w < NW; ++w) {
                f32x4 wf = wp[w];
#pragma unroll
                for (int k = 0; k < RPT; ++k) {
                    float a = acc[k][w];
                    a = fmaf(xA[k].x, wf.x, a);
                    a = fmaf(xA[k].y, wf.y, a);
                    a = fmaf(xA[k].z, wf.z, a);
                    a = fmaf(xA[k].w, wf.w, a);
                    acc[k][w] = a;
                }
            }
        }
        // prefetch column jc
        if (jj + 2 < NJ) {
#pragma unroll
            for (int k = 0; k < RPT; ++k)
                xA[k] = *reinterpret_cast<const f32x4*>(px[k] + (size_t)jc * 32);
        }
        // compute column jb with xB
        {
            const f32x4* wq = &Wl[(jb * 8 + c) * NW];
#pragma unroll
            for (int w = 0; w < NW; ++w) {
                f32x4 wf = wq[w];
#pragma unroll
                for (int k = 0; k < RPT; ++k) {
                    float a = acc[k][w];
                    a = fmaf(xB[k].x, wf.x, a);
                    a = fmaf(xB[k].y, wf.y, a);
                    a = fmaf(xB[k].z, wf.z, a);
                    a = fmaf(xB[k].w, wf.w, a);
                    acc[k][w] = a;
                }
            }
        }
    }

    // ---- Reduce across the 8-lane cluster: xor 1,2,4 ----
#pragma unroll
    for (int k = 0; k < RPT; ++k)
#pragma unroll
        for (int w = 0; w < NW; ++w) {
            float v = acc[k][w];
            v += __shfl_xor(v, 1);
            v += __shfl_xor(v, 2);
            v += __shfl_xor(v, 4);
            acc[k][w] = v;
        }

    // ---- Per row: gate argmax (strict >, first-max tiebreak) + expert select ----
#pragma unroll
    for (int k = 0; k < RPT; ++k) {
        float best = acc[k][0] + gb[0];
        int idx = 0;
#pragma unroll
        for (int e = 1; e < 6; ++e) {
            float v = acc[k][e] + gb[e];
            if (v > best) { best = v; idx = e; }
        }
        float o0 = 0.f, o1 = 0.f;
#pragma unroll
        for (int e = 0; e < 6; ++e) {
            bool m = (idx == e);
            o0 = m ? (acc[k][6 + 2 * e] + eb[2 * e])     : o0;
            o1 = m ? (acc[k][7 + 2 * e] + eb[2 * e + 1]) : o1;
        }
        if (c == 0 && rows[k] < B)
            *reinterpret_cast<float2*>(out + (size_t)rows[k] * 2) = make_float2(o0, o1);
    }
}

extern "C" void kernel_launch(void* const* d_in, const int* in_sizes, int n_in,
                              void* d_out, int out_size, void* d_ws, size_t ws_size,
                              hipStream_t stream) {
    const float* cls      = (const float*)d_in[0];
    const float* gate_w   = (const float*)d_in[1];
    const float* gate_b   = (const float*)d_in[2];
    const float* expert_w = (const float*)d_in[3];
    const float* expert_b = (const float*)d_in[4];
    float* out = (float*)d_out;

    const int B = in_sizes[0] / HDIM;
    const int grid = (B + ROWS_PER_BLOCK - 1) / ROWS_PER_BLOCK;

    hardmoe_kernel<<<grid, NTHREADS, 0, stream>>>(cls, gate_w, gate_b,
                                                  expert_w, expert_b, out, B);
}